// Round 6
// baseline (132.070 us; speedup 1.0000x reference)
//
#include <hip/hip_runtime.h>

// Problem constants
#define BB 32
#define SS 512
#define DD 768
#define HH 12
#define HDIM 64
#define OL 256        // pooled query length
#define NQKV 2304     // 3*DD
#define GM (BB*SS)    // 16384 rows into the QKV GEMM

#define NEG2 (-14426.9504089f)   // -10000 * log2(e)

typedef __bf16 bf16_t;
typedef bf16_t bf16x8 __attribute__((ext_vector_type(8)));
typedef float f32x4 __attribute__((ext_vector_type(4)));
typedef unsigned short u16x8 __attribute__((ext_vector_type(8)));

__device__ __forceinline__ unsigned short f2bf(float f) {
  unsigned u = __float_as_uint(f);
  u = u + 0x7FFFu + ((u >> 16) & 1u);   // RNE
  return (unsigned short)(u >> 16);
}
__device__ __forceinline__ float b2f(unsigned short s) {
  return __uint_as_float(((unsigned)s) << 16);
}

// ---------------------------------------------------------------- conversions
__global__ void conv_f32_bf16(const float* __restrict__ in,
                              unsigned short* __restrict__ out, int n4) {
  int i = blockIdx.x * blockDim.x + threadIdx.x;
  if (i >= n4) return;
  float4 v = ((const float4*)in)[i];
  ushort4 o;
  o.x = f2bf(v.x); o.y = f2bf(v.y); o.z = f2bf(v.z); o.w = f2bf(v.w);
  ((ushort4*)out)[i] = o;
}

// ---------------------------------------------------------------- mask prep
// kbias pre-scaled by log2(e): 0 valid, -14427 masked.
__global__ void prep_mask(const void* __restrict__ mraw,
                          float* __restrict__ kbias,
                          float* __restrict__ invn,
                          unsigned char* __restrict__ nmask,
                          float* __restrict__ out_nm) {
  int b = blockIdx.x, t = threadIdx.x;
  const unsigned char* mb = (const unsigned char*)mraw;
  bool isbyte = (mb[1] != 0);
  int idx = b * SS + t;
  int mv = isbyte ? (int)(mb[idx] != 0) : (int)(((const int*)mraw)[idx] != 0);
  kbias[idx] = mv ? 0.f : NEG2;
  if (t < OL) {
    int i0 = b * SS + 2 * t, i1 = i0 + 1;
    int m0 = isbyte ? (int)(mb[i0] != 0) : (int)(((const int*)mraw)[i0] != 0);
    int m1 = isbyte ? (int)(mb[i1] != 0) : (int)(((const int*)mraw)[i1] != 0);
    int n = m0 + m1;
    invn[b * OL + t] = (n > 0) ? 1.f / (float)n : 1.f;
    nmask[b * OL + t] = (n > 0) ? 1 : 0;
    out_nm[b * OL + t] = (n > 0) ? 1.f : 0.f;   // second tuple output
  }
}

// ---------------------------------------------------------------- QKV GEMM
// 128x128 tile, BK=64, 4 waves (2M x 2N), dbuf LDS 64 KiB -> 2 blocks/CU.
// Counted-vmcnt pipeline, T2 XOR-swizzle, T5 setprio, T1 XCD swizzle.
// Fused epilogues: n-blocks 0-5 -> pooled qp; 6-11 -> Kbuf; 12-17 -> vT.
#define NT 12   // 768 / 64
__global__ __launch_bounds__(256, 2) void gemm_qkv(
    const unsigned short* __restrict__ A,
    const unsigned short* __restrict__ Bt,
    const float* __restrict__ bias,
    unsigned short* __restrict__ Kbuf,   // [B*S][768]
    unsigned short* __restrict__ qp,     // [B*OL][768]
    unsigned short* __restrict__ vT,     // [B][H][64][512]
    const float* __restrict__ kbias,
    const float* __restrict__ invn) {
  __shared__ __align__(16) char smem[65536];  // 2 x (A 16K + B 16K)

  const int t = threadIdx.x;
  const int lane = t & 63;
  const int w = t >> 6;          // 0..3
  const int wm = w >> 1, wn = w & 1;
  const int fr = lane & 15, hi = lane >> 4;

  // T1: bijective XCD-chunk swizzle; 2304 blocks = 8 XCDs x 288 (m-major)
  const int p = blockIdx.x;
  const int l = (p & 7) * 288 + (p >> 3);
  const int m0 = (l / 18) * 128;
  const int n0 = (l % 18) * 128;
  const int b = m0 >> 9;         // batch (128 | 512)
  const int s0 = m0 & 511;       // seq offset of row 0

  f32x4 acc[4][4] = {};

  const int sr8 = lane >> 3;                      // 0..7
  const int sx8 = ((lane & 7) ^ sr8) * 8;         // pre-swizzled src col
  const int wq = __builtin_amdgcn_readfirstlane(w);
  const unsigned short* aSrc = A + (size_t)(m0 + wq * 32 + sr8) * DD + sx8;
  const unsigned short* bSrc = Bt + (size_t)(n0 + wq * 32 + sr8) * DD + sx8;

#define GLOAD(SRC, DST)                                                        \
  __builtin_amdgcn_global_load_lds(                                           \
      (const __attribute__((address_space(1))) unsigned int*)(SRC),           \
      (__attribute__((address_space(3))) unsigned int*)(DST), 16, 0, 0)

  // 8 loads per wave per tile: 4 A-row-chunks + 4 B-row-chunks
#define STAGE(T) do {                                                          \
    char* da_ = smem + ((T) & 1) * 32768;                                      \
    char* db_ = da_ + 16384;                                                   \
    const unsigned short* as_ = aSrc + (T) * 64;                               \
    const unsigned short* bs_ = bSrc + (T) * 64;                               \
    _Pragma("unroll")                                                          \
    for (int i_ = 0; i_ < 4; ++i_) {                                           \
      GLOAD(as_ + (size_t)i_ * 8 * DD, da_ + (wq * 32 + i_ * 8) * 128);        \
      GLOAD(bs_ + (size_t)i_ * 8 * DD, db_ + (wq * 32 + i_ * 8) * 128);        \
    }                                                                          \
  } while (0)

  STAGE(0);
  STAGE(1);

  const int cb0 = (hi * 16) ^ ((fr & 7) << 4);
  const int cb1 = (64 + hi * 16) ^ ((fr & 7) << 4);

  for (int kt = 0; kt < NT; ++kt) {
    if (kt < NT - 1) {
      asm volatile("s_waitcnt vmcnt(8)" ::: "memory");
    } else {
      asm volatile("s_waitcnt vmcnt(0)" ::: "memory");
    }
    __builtin_amdgcn_sched_barrier(0);
    __builtin_amdgcn_s_barrier();
    __builtin_amdgcn_sched_barrier(0);

    const char* bA = smem + (kt & 1) * 32768;
    const char* bB = bA + 16384;

    bf16x8 a0[4], b0[4], a1[4], b1[4];
#pragma unroll
    for (int f = 0; f < 4; ++f) {
      a0[f] = *(const bf16x8*)(bA + (wm * 64 + f * 16 + fr) * 128 + cb0);
      b0[f] = *(const bf16x8*)(bB + (wn * 64 + f * 16 + fr) * 128 + cb0);
    }
    __builtin_amdgcn_sched_barrier(0);
#pragma unroll
    for (int f = 0; f < 4; ++f) {
      a1[f] = *(const bf16x8*)(bA + (wm * 64 + f * 16 + fr) * 128 + cb1);
      b1[f] = *(const bf16x8*)(bB + (wn * 64 + f * 16 + fr) * 128 + cb1);
    }
    asm volatile("s_waitcnt lgkmcnt(8)" ::: "memory");
    __builtin_amdgcn_sched_barrier(0);
    __builtin_amdgcn_s_setprio(1);
#pragma unroll
    for (int mf = 0; mf < 4; ++mf)
#pragma unroll
      for (int nf = 0; nf < 4; ++nf)
        acc[mf][nf] = __builtin_amdgcn_mfma_f32_16x16x32_bf16(
            a0[mf], b0[nf], acc[mf][nf], 0, 0, 0);
    __builtin_amdgcn_s_setprio(0);
    asm volatile("s_waitcnt lgkmcnt(0)" ::: "memory");
    __builtin_amdgcn_sched_barrier(0);
    __builtin_amdgcn_s_barrier();     // all waves done reading this buffer
    __builtin_amdgcn_sched_barrier(0);
    if (kt + 2 < NT) STAGE(kt + 2);   // writes this parity — now safe
    __builtin_amdgcn_sched_barrier(0);
    __builtin_amdgcn_s_setprio(1);
#pragma unroll
    for (int mf = 0; mf < 4; ++mf)
#pragma unroll
      for (int nf = 0; nf < 4; ++nf)
        acc[mf][nf] = __builtin_amdgcn_mfma_f32_16x16x32_bf16(
            a1[mf], b1[nf], acc[mf][nf], 0, 0, 0);
    __builtin_amdgcn_s_setprio(0);
  }
#undef STAGE
#undef GLOAD

  // ---------------- fused epilogues
  const int ntype = n0 / 768;   // 0=Q(pool), 1=K, 2=V(transpose)
  if (ntype == 1) {
#pragma unroll
    for (int nf = 0; nf < 4; ++nf) {
      const int nc = wn * 64 + nf * 16 + fr;
      const float bvs = bias[n0 + nc];
      const int gnc = n0 - 768 + nc;
#pragma unroll
      for (int mf = 0; mf < 4; ++mf) {
        const int gmr = m0 + wm * 64 + mf * 16 + hi * 4;
#pragma unroll
        for (int j = 0; j < 4; ++j)
          Kbuf[(size_t)(gmr + j) * 768 + gnc] = f2bf(acc[mf][nf][j] + bvs);
      }
    }
  } else if (ntype == 0) {
#pragma unroll
    for (int mf = 0; mf < 4; ++mf) {
      const int sl = s0 + wm * 64 + mf * 16 + hi * 4;   // seq of j=0
      const float4 km = *(const float4*)&kbias[b * SS + sl];
      const float2 iv = *(const float2*)&invn[b * OL + (sl >> 1)];
      const float w0 = (km.x == 0.f) ? iv.x : 0.f;
      const float w1 = (km.y == 0.f) ? iv.x : 0.f;
      const float w2 = (km.z == 0.f) ? iv.y : 0.f;
      const float w3 = (km.w == 0.f) ? iv.y : 0.f;
      const int o0 = b * OL + (sl >> 1);
#pragma unroll
      for (int nf = 0; nf < 4; ++nf) {
        const int gnc = n0 + wn * 64 + nf * 16 + fr;
        const float bvs = bias[gnc];
        const f32x4 a = acc[mf][nf];
        qp[(size_t)o0 * DD + gnc] = f2bf((a[0] + bvs) * w0 + (a[1] + bvs) * w1);
        qp[(size_t)(o0 + 1) * DD + gnc] = f2bf((a[2] + bvs) * w2 + (a[3] + bvs) * w3);
      }
    }
  } else {
    // V: bias + bf16 into LDS [128 n][136 m], then transposed coalesced store
    unsigned short* lt = (unsigned short*)smem;
#pragma unroll
    for (int nf = 0; nf < 4; ++nf) {
      const int nl = wn * 64 + nf * 16 + fr;
      const float bvs = bias[n0 + nl];
#pragma unroll
      for (int mf = 0; mf < 4; ++mf) {
        const int mb = wm * 64 + mf * 16 + hi * 4;
        ushort4 pk;
        pk.x = f2bf(acc[mf][nf][0] + bvs);
        pk.y = f2bf(acc[mf][nf][1] + bvs);
        pk.z = f2bf(acc[mf][nf][2] + bvs);
        pk.w = f2bf(acc[mf][nf][3] + bvs);
        *(ushort4*)&lt[nl * 136 + mb] = pk;
      }
    }
    __syncthreads();
#pragma unroll
    for (int i = 0; i < 8; ++i) {
      const int row = i * 16 + (t >> 4);
      const int ch = t & 15;
      const u16x8 v = *(const u16x8*)&lt[row * 136 + ch * 8];
      const int n = n0 - 1536 + row;
      const int h2 = n >> 6, d2 = n & 63;
      *(u16x8*)(vT + ((size_t)((b * HH + h2) * HDIM + d2)) * 512 + s0 + ch * 8) = v;
    }
  }
}

// ---------------------------------------------------------------- attention
// slopes pre-scaled by log2(e)
__constant__ float c_slopes2[12] = {
    0.72134752f, 0.36067376f, 0.18033688f, 0.09016844f,
    0.04508422f, 0.02254211f, 0.011271055f, 0.0056355275f,
    1.02013945f, 0.51006972f, 0.25503486f, 0.12751743f};

// 4-wave block per (b,h); wave w owns q-tile w*64. K/V dbuf SHARED across
// waves (staged cooperatively, 4 loads/wave/tile, counted vmcnt(4)), P
// per-wave, fixed-max log2-domain softmax.
// LDS: kt dbuf 0..16K, vt dbuf 16..32K, P 32K + w*8K, kb @65536 (2K).
// Epilogue: per-wave 64x68 f32 tile at w*17408 (reuses everything).
__global__ __launch_bounds__(256) void attn_mfma(
    const unsigned short* __restrict__ qp,    // [B][OL][768] bf16
    const unsigned short* __restrict__ Kb,    // [B*S][768] bf16
    const unsigned short* __restrict__ vT,    // [B][H][64][512] bf16
    const float* __restrict__ kbias,          // [B][S], pre-scaled log2e
    const unsigned char* __restrict__ nmask,  // [B][OL]
    float* __restrict__ out) {                // [B][OL][768]
  __shared__ __align__(16) char smem[69632];
  const int t = threadIdx.x;
  const int lane = t & 63;
  const int w = t >> 6;
  const int wq = __builtin_amdgcn_readfirstlane(w);
  const int fr = lane & 15, hi = lane >> 4;

  // 384 blocks = 8 XCDs x 48
  const int p = blockIdx.x;
  const int l = (p & 7) * 48 + (p >> 3);
  const int h = l % HH, b = l / HH;
  const int q0 = wq * 64;

  char* ptb = smem + 32768 + wq * 8192;
  float* kbl = (float*)(smem + 65536);

  const int srow = lane >> 3;
  const int scol = ((lane & 7) ^ srow) * 8;

#define GLOAD(SRC, DST)                                                        \
  __builtin_amdgcn_global_load_lds(                                           \
      (const __attribute__((address_space(1))) unsigned int*)(SRC),           \
      (__attribute__((address_space(3))) unsigned int*)(DST), 16, 0, 0)

  // kbias row -> LDS via DMA (wave 0 only; 2 issues, part of vmcnt ledger)
  if (wq == 0) {
    GLOAD(kbias + b * SS + lane * 4, smem + 65536);
    GLOAD(kbias + b * SS + 256 + lane * 4, smem + 66560);
  }

  // Q fragments: A-operand, row = q0+m*16+fr, k(d) = ks*32 + hi*8 (+0..7)
  bf16x8 qf[4][2];
#pragma unroll
  for (int m = 0; m < 4; ++m)
#pragma unroll
    for (int ks = 0; ks < 2; ++ks)
      qf[m][ks] = *(const bf16x8*)(qp + (size_t)(b * OL + q0 + m * 16 + fr) * DD +
                                   h * HDIM + ks * 32 + hi * 8);

  // one nmask byte per lane, distribute via shuffles
  int nmv = (int)nmask[b * OL + q0 + lane];
  int qmbits = 0;
#pragma unroll
  for (int m = 0; m < 4; ++m)
#pragma unroll
    for (int j = 0; j < 4; ++j)
      if (__shfl(nmv, m * 16 + hi * 4 + j, 64)) qmbits |= 1 << (m * 4 + j);

  const float slope2 = c_slopes2[h];
  f32x4 oacc[4][4] = {};
  float lpart[4][4] = {};

  // wave w stages K rows [w*16, w*16+16) and V rows [w*16, w*16+16)
#define STAGE(TILE, BUF) do {                                                  \
    char* kd_ = smem + (BUF) * 8192 + wq * 2048;                               \
    char* vd_ = smem + 16384 + (BUF) * 8192 + wq * 2048;                       \
    const unsigned short* ks_ =                                                \
        Kb + (size_t)(b * SS + (TILE) * 64 + wq * 16 + srow) * 768 + h * HDIM + scol; \
    const unsigned short* vs_ =                                                \
        vT + (size_t)((b * HH + h) * HDIM + wq * 16 + srow) * SS + (TILE) * 64 + scol; \
    GLOAD(ks_, kd_);                                                           \
    GLOAD(ks_ + (size_t)8 * 768, kd_ + 1024);                                  \
    GLOAD(vs_, vd_);                                                           \
    GLOAD(vs_ + (size_t)8 * SS, vd_ + 1024);                                   \
  } while (0)

  __builtin_amdgcn_sched_barrier(0);
  STAGE(0, 0);
  STAGE(1, 1);
  __builtin_amdgcn_sched_barrier(0);

  for (int tile = 0; tile < 8; ++tile) {
    const int cur = tile & 1;
    const int key0 = tile * 64;
    if (tile < 7) {
      asm volatile("s_waitcnt vmcnt(4)" ::: "memory");
    } else {
      asm volatile("s_waitcnt vmcnt(0)" ::: "memory");
    }
    __builtin_amdgcn_sched_barrier(0);
    __builtin_amdgcn_s_barrier();          // all waves' tile data landed
    __builtin_amdgcn_sched_barrier(0);

    char* ktb = smem + cur * 8192;
    char* vtb = smem + 16384 + cur * 8192;

    // ---- QK^T
    f32x4 sacc[4][4] = {};
#pragma unroll
    for (int ks = 0; ks < 2; ++ks) {
      bf16x8 kf[4];
#pragma unroll
      for (int n = 0; n < 4; ++n) {
        const int by = ((n * 16 + fr) * 128 + (ks * 64 + hi * 16)) ^ ((fr & 7) << 4);
        kf[n] = *(const bf16x8*)(ktb + by);
      }
#pragma unroll
      for (int m = 0; m < 4; ++m)
#pragma unroll
        for (int n = 0; n < 4; ++n)
          sacc[m][n] = __builtin_amdgcn_mfma_f32_16x16x32_bf16(qf[m][ks], kf[n], sacc[m][n], 0, 0, 0);
    }

    // ---- fixed-max log2-domain softmax; P -> LDS (bf16)
    float kbv[4], keyfv[4];
#pragma unroll
    for (int n = 0; n < 4; ++n) {
      kbv[n] = kbl[key0 + n * 16 + fr];
      keyfv[n] = (float)(key0 + n * 16 + fr);
    }
#pragma unroll
    for (int m = 0; m < 4; ++m) {
#pragma unroll
      for (int j = 0; j < 4; ++j) {
        const bool qm = (qmbits >> (m * 4 + j)) & 1;
        const float qvf = (float)(q0 + m * 16 + hi * 4 + j);
        float lp = lpart[m][j];
#pragma unroll
        for (int n = 0; n < 4; ++n) {
          const float biasv = qm ? kbv[n] : 0.f;
          const float rel = fabsf(keyfv[n] - qvf);
          float tv = fmaf(sacc[m][n][j], 0.18033688011f, biasv);
          tv = fmaf(rel, -slope2, tv);
          float pe;
          asm("v_exp_f32 %0, %1" : "=v"(pe) : "v"(tv));
          lp += pe;
          const int by = ((m * 16 + hi * 4 + j) * 128 + (n * 16 + fr) * 2) ^
                         (((hi * 4 + j) & 7) << 4);
          *(unsigned short*)(ptb + by) = f2bf(pe);
        }
        lpart[m][j] = lp;
      }
    }
    asm volatile("s_waitcnt lgkmcnt(0)" ::: "memory");
    __builtin_amdgcn_sched_barrier(0);

    // ---- PV
#pragma unroll
    for (int ks = 0; ks < 2; ++ks) {
      bf16x8 pf[4], vf[4];
#pragma unroll
      for (int m = 0; m < 4; ++m) {
        const int by = ((m * 16 + fr) * 128 + (ks * 64 + hi * 16)) ^ ((fr & 7) << 4);
        pf[m] = *(const bf16x8*)(ptb + by);
      }
#pragma unroll
      for (int nd = 0; nd < 4; ++nd) {
        const int by = ((nd * 16 + fr) * 128 + (ks * 64 + hi * 16)) ^ ((fr & 7) << 4);
        vf[nd] = *(const bf16x8*)(vtb + by);
      }
#pragma unroll
      for (int m = 0; m < 4; ++m)
#pragma unroll
        for (int nd = 0; nd < 4; ++nd)
          oacc[m][nd] = __builtin_amdgcn_mfma_f32_16x16x32_bf16(pf[m], vf[nd], oacc[m][nd], 0, 0, 0);
    }

    __builtin_amdgcn_sched_barrier(0);
    __builtin_amdgcn_s_barrier();          // all waves done reading buf `cur`
    __builtin_amdgcn_sched_barrier(0);
    if (tile + 2 < 8) STAGE(tile + 2, cur);
  }
#undef STAGE
#undef GLOAD

  // ---- epilogue: reduce l, normalize, transpose via per-wave LDS tile,
  //      coalesced stores. (last loop barrier guarantees LDS is free)
  float* ot = (float*)(smem + wq * 17408);   // 64 x 68 f32
#pragma unroll
  for (int m = 0; m < 4; ++m)
#pragma unroll
    for (int j = 0; j < 4; ++j) {
      float lv = lpart[m][j];
      lv += __shfl_xor(lv, 1, 64);
      lv += __shfl_xor(lv, 2, 64);
      lv += __shfl_xor(lv, 4, 64);
      lv += __shfl_xor(lv, 8, 64);
      const float rl = 1.f / lv;
      const int row = m * 16 + hi * 4 + j;
#pragma unroll
      for (int nd = 0; nd < 4; ++nd)
        ot[row * 68 + nd * 16 + fr] = oacc[m][nd][j] * rl;
    }
  asm volatile("s_waitcnt lgkmcnt(0)" ::: "memory");
  __builtin_amdgcn_sched_barrier(0);
#pragma unroll
  for (int i = 0; i < 16; ++i) {
    const int idx = i * 64 + lane;       // float4 index
    const int row = idx >> 4, c4 = idx & 15;
    const float4 v = *(const float4*)&ot[row * 68 + c4 * 4];
    *(float4*)(out + (size_t)(b * OL + q0 + row) * DD + h * HDIM + c4 * 4) = v;
  }
}

// ---------------------------------------------------------------- launch
extern "C" void kernel_launch(void* const* d_in, const int* in_sizes, int n_in,
                              void* d_out, int out_size, void* d_ws, size_t ws_size,
                              hipStream_t stream) {
  const float* hidden = (const float*)d_in[0];
  const void* maskraw = d_in[1];
  const float* W = (const float*)d_in[2];
  const float* bias = (const float*)d_in[3];
  float* out = (float*)d_out;

  char* ws = (char*)d_ws;
  unsigned short* Abf  = (unsigned short*)(ws);                 // 25,165,824 B
  unsigned short* Btb  = (unsigned short*)(ws + 25165824);      //  3,538,944 B
  unsigned short* Kbuf = (unsigned short*)(ws + 28704768);      // 25,165,824 B
  unsigned short* vT   = (unsigned short*)(ws + 53870592);      // 25,165,824 B
  unsigned short* qp   = (unsigned short*)(ws + 79036416);      // 12,582,912 B
  float* kbias         = (float*)(ws + 91619328);               //     65,536 B
  float* invn          = (float*)(ws + 91684864);               //     32,768 B
  unsigned char* nmask = (unsigned char*)(ws + 91717632);       //      8,192 B

  float* out_nm = out + (size_t)BB * OL * DD;  // new_mask part of d_out

  conv_f32_bf16<<<(GM * DD / 4 + 255) / 256, 256, 0, stream>>>(hidden, Abf, GM * DD / 4);
  conv_f32_bf16<<<(NQKV * DD / 4 + 255) / 256, 256, 0, stream>>>(W, Btb, NQKV * DD / 4);
  prep_mask<<<BB, SS, 0, stream>>>(maskraw, kbias, invn, nmask, out_nm);
  gemm_qkv<<<2304, 256, 0, stream>>>(Abf, Btb, bias, Kbuf, qp, vT, kbias, invn);
  attn_mfma<<<384, 256, 0, stream>>>(qp, Kbuf, vT, kbias, nmask, out);
}

// Round 7
// 112.556 us; speedup vs baseline: 1.1734x; 1.1734x over previous
//
#include <hip/hip_runtime.h>

// Problem constants
#define BB 32
#define SS 512
#define DD 768
#define HH 12
#define HDIM 64
#define OL 256        // pooled query length
#define NQKV 2304     // 3*DD
#define GM (BB*SS)    // 16384 rows into the QKV GEMM

#define NEG2 (-14426.9504089f)   // -10000 * log2(e)

typedef __bf16 bf16_t;
typedef bf16_t bf16x8 __attribute__((ext_vector_type(8)));
typedef float f32x4 __attribute__((ext_vector_type(4)));
typedef unsigned short u16x8 __attribute__((ext_vector_type(8)));

__device__ __forceinline__ unsigned short f2bf(float f) {
  unsigned u = __float_as_uint(f);
  u = u + 0x7FFFu + ((u >> 16) & 1u);   // RNE
  return (unsigned short)(u >> 16);
}
__device__ __forceinline__ float b2f(unsigned short s) {
  return __uint_as_float(((unsigned)s) << 16);
}

// ---------------------------------------------------------------- conversions
__global__ void conv_f32_bf16(const float* __restrict__ in,
                              unsigned short* __restrict__ out, int n4) {
  int i = blockIdx.x * blockDim.x + threadIdx.x;
  if (i >= n4) return;
  float4 v = ((const float4*)in)[i];
  ushort4 o;
  o.x = f2bf(v.x); o.y = f2bf(v.y); o.z = f2bf(v.z); o.w = f2bf(v.w);
  ((ushort4*)out)[i] = o;
}

// ---------------------------------------------------------------- mask prep
// kbias pre-scaled by log2(e): 0 valid, -14427 masked.
__global__ void prep_mask(const void* __restrict__ mraw,
                          float* __restrict__ kbias,
                          float* __restrict__ invn,
                          unsigned char* __restrict__ nmask,
                          float* __restrict__ out_nm) {
  int b = blockIdx.x, t = threadIdx.x;
  const unsigned char* mb = (const unsigned char*)mraw;
  bool isbyte = (mb[1] != 0);
  int idx = b * SS + t;
  int mv = isbyte ? (int)(mb[idx] != 0) : (int)(((const int*)mraw)[idx] != 0);
  kbias[idx] = mv ? 0.f : NEG2;
  if (t < OL) {
    int i0 = b * SS + 2 * t, i1 = i0 + 1;
    int m0 = isbyte ? (int)(mb[i0] != 0) : (int)(((const int*)mraw)[i0] != 0);
    int m1 = isbyte ? (int)(mb[i1] != 0) : (int)(((const int*)mraw)[i1] != 0);
    int n = m0 + m1;
    invn[b * OL + t] = (n > 0) ? 1.f / (float)n : 1.f;
    nmask[b * OL + t] = (n > 0) ? 1 : 0;
    out_nm[b * OL + t] = (n > 0) ? 1.f : 0.f;   // second tuple output
  }
}

// ---------------------------------------------------------------- QKV GEMM
// 128x128 tile, BK=64, 4 waves (2M x 2N), dbuf LDS 64 KiB -> 2 blocks/CU.
// Counted-vmcnt pipeline, T2 XOR-swizzle, T5 setprio, T1 XCD swizzle.
// Fused epilogues: n-blocks 0-5 -> pooled qp; 6-11 -> Kbuf; 12-17 -> vT.
#define NT 12   // 768 / 64
__global__ __launch_bounds__(256, 2) void gemm_qkv(
    const unsigned short* __restrict__ A,
    const unsigned short* __restrict__ Bt,
    const float* __restrict__ bias,
    unsigned short* __restrict__ Kbuf,   // [B*S][768]
    unsigned short* __restrict__ qp,     // [B*OL][768]
    unsigned short* __restrict__ vT,     // [B][H][64][512]
    const float* __restrict__ kbias,
    const float* __restrict__ invn) {
  __shared__ __align__(16) char smem[65536];  // 2 x (A 16K + B 16K)

  const int t = threadIdx.x;
  const int lane = t & 63;
  const int w = t >> 6;          // 0..3
  const int wm = w >> 1, wn = w & 1;
  const int fr = lane & 15, hi = lane >> 4;

  // T1: bijective XCD-chunk swizzle; 2304 blocks = 8 XCDs x 288 (m-major)
  const int p = blockIdx.x;
  const int l = (p & 7) * 288 + (p >> 3);
  const int m0 = (l / 18) * 128;
  const int n0 = (l % 18) * 128;
  const int b = m0 >> 9;         // batch (128 | 512)
  const int s0 = m0 & 511;       // seq offset of row 0

  f32x4 acc[4][4] = {};

  const int sr8 = lane >> 3;                      // 0..7
  const int sx8 = ((lane & 7) ^ sr8) * 8;         // pre-swizzled src col
  const int wq = __builtin_amdgcn_readfirstlane(w);
  const unsigned short* aSrc = A + (size_t)(m0 + wq * 32 + sr8) * DD + sx8;
  const unsigned short* bSrc = Bt + (size_t)(n0 + wq * 32 + sr8) * DD + sx8;

#define GLOAD(SRC, DST)                                                        \
  __builtin_amdgcn_global_load_lds(                                           \
      (const __attribute__((address_space(1))) unsigned int*)(SRC),           \
      (__attribute__((address_space(3))) unsigned int*)(DST), 16, 0, 0)

  // 8 loads per wave per tile: 4 A-row-chunks + 4 B-row-chunks
#define STAGE(T) do {                                                          \
    char* da_ = smem + ((T) & 1) * 32768;                                      \
    char* db_ = da_ + 16384;                                                   \
    const unsigned short* as_ = aSrc + (T) * 64;                               \
    const unsigned short* bs_ = bSrc + (T) * 64;                               \
    _Pragma("unroll")                                                          \
    for (int i_ = 0; i_ < 4; ++i_) {                                           \
      GLOAD(as_ + (size_t)i_ * 8 * DD, da_ + (wq * 32 + i_ * 8) * 128);        \
      GLOAD(bs_ + (size_t)i_ * 8 * DD, db_ + (wq * 32 + i_ * 8) * 128);        \
    }                                                                          \
  } while (0)

  STAGE(0);
  STAGE(1);

  const int cb0 = (hi * 16) ^ ((fr & 7) << 4);
  const int cb1 = (64 + hi * 16) ^ ((fr & 7) << 4);

  for (int kt = 0; kt < NT; ++kt) {
    if (kt < NT - 1) {
      asm volatile("s_waitcnt vmcnt(8)" ::: "memory");
    } else {
      asm volatile("s_waitcnt vmcnt(0)" ::: "memory");
    }
    __builtin_amdgcn_sched_barrier(0);
    __builtin_amdgcn_s_barrier();
    __builtin_amdgcn_sched_barrier(0);

    const char* bA = smem + (kt & 1) * 32768;
    const char* bB = bA + 16384;

    bf16x8 a0[4], b0[4], a1[4], b1[4];
#pragma unroll
    for (int f = 0; f < 4; ++f) {
      a0[f] = *(const bf16x8*)(bA + (wm * 64 + f * 16 + fr) * 128 + cb0);
      b0[f] = *(const bf16x8*)(bB + (wn * 64 + f * 16 + fr) * 128 + cb0);
    }
    __builtin_amdgcn_sched_barrier(0);
#pragma unroll
    for (int f = 0; f < 4; ++f) {
      a1[f] = *(const bf16x8*)(bA + (wm * 64 + f * 16 + fr) * 128 + cb1);
      b1[f] = *(const bf16x8*)(bB + (wn * 64 + f * 16 + fr) * 128 + cb1);
    }
    asm volatile("s_waitcnt lgkmcnt(8)" ::: "memory");
    __builtin_amdgcn_sched_barrier(0);
    __builtin_amdgcn_s_setprio(1);
#pragma unroll
    for (int mf = 0; mf < 4; ++mf)
#pragma unroll
      for (int nf = 0; nf < 4; ++nf)
        acc[mf][nf] = __builtin_amdgcn_mfma_f32_16x16x32_bf16(
            a0[mf], b0[nf], acc[mf][nf], 0, 0, 0);
    __builtin_amdgcn_s_setprio(0);
    asm volatile("s_waitcnt lgkmcnt(0)" ::: "memory");
    __builtin_amdgcn_sched_barrier(0);
    __builtin_amdgcn_s_barrier();     // all waves done reading this buffer
    __builtin_amdgcn_sched_barrier(0);
    if (kt + 2 < NT) STAGE(kt + 2);   // writes this parity — now safe
    __builtin_amdgcn_sched_barrier(0);
    __builtin_amdgcn_s_setprio(1);
#pragma unroll
    for (int mf = 0; mf < 4; ++mf)
#pragma unroll
      for (int nf = 0; nf < 4; ++nf)
        acc[mf][nf] = __builtin_amdgcn_mfma_f32_16x16x32_bf16(
            a1[mf], b1[nf], acc[mf][nf], 0, 0, 0);
    __builtin_amdgcn_s_setprio(0);
  }
#undef STAGE
#undef GLOAD

  // ---------------- fused epilogues
  const int ntype = n0 / 768;   // 0=Q(pool), 1=K, 2=V(transpose)
  if (ntype == 1) {
#pragma unroll
    for (int nf = 0; nf < 4; ++nf) {
      const int nc = wn * 64 + nf * 16 + fr;
      const float bvs = bias[n0 + nc];
      const int gnc = n0 - 768 + nc;
#pragma unroll
      for (int mf = 0; mf < 4; ++mf) {
        const int gmr = m0 + wm * 64 + mf * 16 + hi * 4;
#pragma unroll
        for (int j = 0; j < 4; ++j)
          Kbuf[(size_t)(gmr + j) * 768 + gnc] = f2bf(acc[mf][nf][j] + bvs);
      }
    }
  } else if (ntype == 0) {
#pragma unroll
    for (int mf = 0; mf < 4; ++mf) {
      const int sl = s0 + wm * 64 + mf * 16 + hi * 4;   // seq of j=0
      const float4 km = *(const float4*)&kbias[b * SS + sl];
      const float2 iv = *(const float2*)&invn[b * OL + (sl >> 1)];
      const float w0 = (km.x == 0.f) ? iv.x : 0.f;
      const float w1 = (km.y == 0.f) ? iv.x : 0.f;
      const float w2 = (km.z == 0.f) ? iv.y : 0.f;
      const float w3 = (km.w == 0.f) ? iv.y : 0.f;
      const int o0 = b * OL + (sl >> 1);
#pragma unroll
      for (int nf = 0; nf < 4; ++nf) {
        const int gnc = n0 + wn * 64 + nf * 16 + fr;
        const float bvs = bias[gnc];
        const f32x4 a = acc[mf][nf];
        qp[(size_t)o0 * DD + gnc] = f2bf((a[0] + bvs) * w0 + (a[1] + bvs) * w1);
        qp[(size_t)(o0 + 1) * DD + gnc] = f2bf((a[2] + bvs) * w2 + (a[3] + bvs) * w3);
      }
    }
  } else {
    // V: bias + bf16 into LDS [128 n][136 m], then transposed coalesced store
    unsigned short* lt = (unsigned short*)smem;
#pragma unroll
    for (int nf = 0; nf < 4; ++nf) {
      const int nl = wn * 64 + nf * 16 + fr;
      const float bvs = bias[n0 + nl];
#pragma unroll
      for (int mf = 0; mf < 4; ++mf) {
        const int mb = wm * 64 + mf * 16 + hi * 4;
        ushort4 pk;
        pk.x = f2bf(acc[mf][nf][0] + bvs);
        pk.y = f2bf(acc[mf][nf][1] + bvs);
        pk.z = f2bf(acc[mf][nf][2] + bvs);
        pk.w = f2bf(acc[mf][nf][3] + bvs);
        *(ushort4*)&lt[nl * 136 + mb] = pk;
      }
    }
    __syncthreads();
#pragma unroll
    for (int i = 0; i < 8; ++i) {
      const int row = i * 16 + (t >> 4);
      const int ch = t & 15;
      const u16x8 v = *(const u16x8*)&lt[row * 136 + ch * 8];
      const int n = n0 - 1536 + row;
      const int h2 = n >> 6, d2 = n & 63;
      *(u16x8*)(vT + ((size_t)((b * HH + h2) * HDIM + d2)) * 512 + s0 + ch * 8) = v;
    }
  }
}

// ---------------------------------------------------------------- attention
// slopes pre-scaled by log2(e)
__constant__ float c_slopes2[12] = {
    0.72134752f, 0.36067376f, 0.18033688f, 0.09016844f,
    0.04508422f, 0.02254211f, 0.011271055f, 0.0056355275f,
    1.02013945f, 0.51006972f, 0.25503486f, 0.12751743f};

// 4-wave block; block covers HALF the q-rows of one (b,h): wave w owns
// 32 q-rows (2 m-frags). 768 blocks x 4 waves = 3072 waves = 3/SIMD.
// K/V dbuf shared across waves (4 loads/wave/tile, counted vmcnt(4)),
// per-wave P (4 KiB), fixed-max log2-domain softmax.
// LDS: kt dbuf 0..16K, vt dbuf 16..32K, P 32K + w*4K, kb @49152 (2K).
// Total 51200 B -> 3 blocks/CU. Epilogue reuses [0, 34816).
__global__ __launch_bounds__(256) void attn_mfma(
    const unsigned short* __restrict__ qp,    // [B][OL][768] bf16
    const unsigned short* __restrict__ Kb,    // [B*S][768] bf16
    const unsigned short* __restrict__ vT,    // [B][H][64][512] bf16
    const float* __restrict__ kbias,          // [B][S], pre-scaled log2e
    const unsigned char* __restrict__ nmask,  // [B][OL]
    float* __restrict__ out) {                // [B][OL][768]
  __shared__ __align__(16) char smem[51200];
  const int t = threadIdx.x;
  const int lane = t & 63;
  const int w = t >> 6;
  const int wq = __builtin_amdgcn_readfirstlane(w);
  const int fr = lane & 15, hi = lane >> 4;

  // 768 blocks = 8 XCDs x 96; consecutive logical ids share (b,h) -> L2 reuse
  const int p = blockIdx.x;
  const int l = (p & 7) * 96 + (p >> 3);
  const int qb = l & 1;
  const int bh = l >> 1;
  const int h = bh % HH, b = bh / HH;
  const int q0 = qb * 128 + wq * 32;    // this wave's first q-row

  char* ptb = smem + 32768 + wq * 4096;
  float* kbl = (float*)(smem + 49152);

  const int srow = lane >> 3;
  const int scol = ((lane & 7) ^ srow) * 8;

#define GLOAD(SRC, DST)                                                        \
  __builtin_amdgcn_global_load_lds(                                           \
      (const __attribute__((address_space(1))) unsigned int*)(SRC),           \
      (__attribute__((address_space(3))) unsigned int*)(DST), 16, 0, 0)

  // kbias row -> LDS via DMA (wave 0 only; 2 issues, drained by 1st vmcnt(4))
  if (wq == 0) {
    GLOAD(kbias + b * SS + lane * 4, smem + 49152);
    GLOAD(kbias + b * SS + 256 + lane * 4, smem + 50176);
  }

  // Q fragments: A-operand, row = q0+m*16+fr, k(d) = ks*32 + hi*8 (+0..7)
  bf16x8 qf[2][2];
#pragma unroll
  for (int m = 0; m < 2; ++m)
#pragma unroll
    for (int ks = 0; ks < 2; ++ks)
      qf[m][ks] = *(const bf16x8*)(qp + (size_t)(b * OL + q0 + m * 16 + fr) * DD +
                                   h * HDIM + ks * 32 + hi * 8);

  // one nmask byte per lane (32 rows -> lane&31), distribute via shuffles
  int nmv = (int)nmask[b * OL + q0 + (lane & 31)];
  int qmbits = 0;
#pragma unroll
  for (int m = 0; m < 2; ++m)
#pragma unroll
    for (int j = 0; j < 4; ++j)
      if (__shfl(nmv, m * 16 + hi * 4 + j, 64)) qmbits |= 1 << (m * 4 + j);

  const float slope2 = c_slopes2[h];
  f32x4 oacc[2][4] = {};
  float lpart[2][4] = {};

  // wave w stages K rows [w*16, w*16+16) and V rows [w*16, w*16+16)
#define STAGE(TILE, BUF) do {                                                  \
    char* kd_ = smem + (BUF) * 8192 + wq * 2048;                               \
    char* vd_ = smem + 16384 + (BUF) * 8192 + wq * 2048;                       \
    const unsigned short* ks_ =                                                \
        Kb + (size_t)(b * SS + (TILE) * 64 + wq * 16 + srow) * 768 + h * HDIM + scol; \
    const unsigned short* vs_ =                                                \
        vT + (size_t)((b * HH + h) * HDIM + wq * 16 + srow) * SS + (TILE) * 64 + scol; \
    GLOAD(ks_, kd_);                                                           \
    GLOAD(ks_ + (size_t)8 * 768, kd_ + 1024);                                  \
    GLOAD(vs_, vd_);                                                           \
    GLOAD(vs_ + (size_t)8 * SS, vd_ + 1024);                                   \
  } while (0)

  __builtin_amdgcn_sched_barrier(0);
  STAGE(0, 0);
  STAGE(1, 1);
  __builtin_amdgcn_sched_barrier(0);

  for (int tile = 0; tile < 8; ++tile) {
    const int cur = tile & 1;
    const int key0 = tile * 64;
    if (tile < 7) {
      asm volatile("s_waitcnt vmcnt(4)" ::: "memory");
    } else {
      asm volatile("s_waitcnt vmcnt(0)" ::: "memory");
    }
    __builtin_amdgcn_sched_barrier(0);
    __builtin_amdgcn_s_barrier();          // all waves' tile data landed
    __builtin_amdgcn_sched_barrier(0);

    char* ktb = smem + cur * 8192;
    char* vtb = smem + 16384 + cur * 8192;

    // ---- QK^T
    f32x4 sacc[2][4] = {};
#pragma unroll
    for (int ks = 0; ks < 2; ++ks) {
      bf16x8 kf[4];
#pragma unroll
      for (int n = 0; n < 4; ++n) {
        const int by = ((n * 16 + fr) * 128 + (ks * 64 + hi * 16)) ^ ((fr & 7) << 4);
        kf[n] = *(const bf16x8*)(ktb + by);
      }
#pragma unroll
      for (int m = 0; m < 2; ++m)
#pragma unroll
        for (int n = 0; n < 4; ++n)
          sacc[m][n] = __builtin_amdgcn_mfma_f32_16x16x32_bf16(qf[m][ks], kf[n], sacc[m][n], 0, 0, 0);
    }

    // ---- fixed-max log2-domain softmax; P -> LDS (bf16)
    float kbv[4], keyfv[4];
#pragma unroll
    for (int n = 0; n < 4; ++n) {
      kbv[n] = kbl[key0 + n * 16 + fr];
      keyfv[n] = (float)(key0 + n * 16 + fr);
    }
#pragma unroll
    for (int m = 0; m < 2; ++m) {
#pragma unroll
      for (int j = 0; j < 4; ++j) {
        const bool qm = (qmbits >> (m * 4 + j)) & 1;
        const float qvf = (float)(q0 + m * 16 + hi * 4 + j);
        float lp = lpart[m][j];
#pragma unroll
        for (int n = 0; n < 4; ++n) {
          const float biasv = qm ? kbv[n] : 0.f;
          const float rel = fabsf(keyfv[n] - qvf);
          float tv = fmaf(sacc[m][n][j], 0.18033688011f, biasv);
          tv = fmaf(rel, -slope2, tv);
          float pe;
          asm("v_exp_f32 %0, %1" : "=v"(pe) : "v"(tv));
          lp += pe;
          const int by = ((m * 16 + hi * 4 + j) * 128 + (n * 16 + fr) * 2) ^
                         (((hi * 4 + j) & 7) << 4);
          *(unsigned short*)(ptb + by) = f2bf(pe);
        }
        lpart[m][j] = lp;
      }
    }
    asm volatile("s_waitcnt lgkmcnt(0)" ::: "memory");
    __builtin_amdgcn_sched_barrier(0);

    // ---- PV
#pragma unroll
    for (int ks = 0; ks < 2; ++ks) {
      bf16x8 pf[2], vf[4];
#pragma unroll
      for (int m = 0; m < 2; ++m) {
        const int by = ((m * 16 + fr) * 128 + (ks * 64 + hi * 16)) ^ ((fr & 7) << 4);
        pf[m] = *(const bf16x8*)(ptb + by);
      }
#pragma unroll
      for (int nd = 0; nd < 4; ++nd) {
        const int by = ((nd * 16 + fr) * 128 + (ks * 64 + hi * 16)) ^ ((fr & 7) << 4);
        vf[nd] = *(const bf16x8*)(vtb + by);
      }
#pragma unroll
      for (int m = 0; m < 2; ++m)
#pragma unroll
        for (int nd = 0; nd < 4; ++nd)
          oacc[m][nd] = __builtin_amdgcn_mfma_f32_16x16x32_bf16(pf[m], vf[nd], oacc[m][nd], 0, 0, 0);
    }

    __builtin_amdgcn_sched_barrier(0);
    __builtin_amdgcn_s_barrier();          // all waves done reading buf `cur`
    __builtin_amdgcn_sched_barrier(0);
    if (tile + 2 < 8) STAGE(tile + 2, cur);
  }
#undef STAGE
#undef GLOAD

  // ---- epilogue: reduce l, normalize, transpose via per-wave LDS tile,
  //      coalesced stores. (last loop barrier guarantees LDS is free)
  float* ot = (float*)(smem + wq * 8704);   // 32 x 68 f32
#pragma unroll
  for (int m = 0; m < 2; ++m)
#pragma unroll
    for (int j = 0; j < 4; ++j) {
      float lv = lpart[m][j];
      lv += __shfl_xor(lv, 1, 64);
      lv += __shfl_xor(lv, 2, 64);
      lv += __shfl_xor(lv, 4, 64);
      lv += __shfl_xor(lv, 8, 64);
      const float rl = 1.f / lv;
      const int row = m * 16 + hi * 4 + j;
#pragma unroll
      for (int nd = 0; nd < 4; ++nd)
        ot[row * 68 + nd * 16 + fr] = oacc[m][nd][j] * rl;
    }
  asm volatile("s_waitcnt lgkmcnt(0)" ::: "memory");
  __builtin_amdgcn_sched_barrier(0);
#pragma unroll
  for (int i = 0; i < 8; ++i) {
    const int idx = i * 64 + lane;       // float4 index, 512 per wave
    const int row = idx >> 4, c4 = idx & 15;
    const float4 v = *(const float4*)&ot[row * 68 + c4 * 4];
    *(float4*)(out + (size_t)(b * OL + q0 + row) * DD + h * HDIM + c4 * 4) = v;
  }
}

// ---------------------------------------------------------------- launch
extern "C" void kernel_launch(void* const* d_in, const int* in_sizes, int n_in,
                              void* d_out, int out_size, void* d_ws, size_t ws_size,
                              hipStream_t stream) {
  const float* hidden = (const float*)d_in[0];
  const void* maskraw = d_in[1];
  const float* W = (const float*)d_in[2];
  const float* bias = (const float*)d_in[3];
  float* out = (float*)d_out;

  char* ws = (char*)d_ws;
  unsigned short* Abf  = (unsigned short*)(ws);                 // 25,165,824 B
  unsigned short* Btb  = (unsigned short*)(ws + 25165824);      //  3,538,944 B
  unsigned short* Kbuf = (unsigned short*)(ws + 28704768);      // 25,165,824 B
  unsigned short* vT   = (unsigned short*)(ws + 53870592);      // 25,165,824 B
  unsigned short* qp   = (unsigned short*)(ws + 79036416);      // 12,582,912 B
  float* kbias         = (float*)(ws + 91619328);               //     65,536 B
  float* invn          = (float*)(ws + 91684864);               //     32,768 B
  unsigned char* nmask = (unsigned char*)(ws + 91717632);       //      8,192 B

  float* out_nm = out + (size_t)BB * OL * DD;  // new_mask part of d_out

  conv_f32_bf16<<<(GM * DD / 4 + 255) / 256, 256, 0, stream>>>(hidden, Abf, GM * DD / 4);
  conv_f32_bf16<<<(NQKV * DD / 4 + 255) / 256, 256, 0, stream>>>(W, Btb, NQKV * DD / 4);
  prep_mask<<<BB, SS, 0, stream>>>(maskraw, kbias, invn, nmask, out_nm);
  gemm_qkv<<<2304, 256, 0, stream>>>(Abf, Btb, bias, Kbuf, qp, vT, kbias, invn);
  attn_mfma<<<768, 256, 0, stream>>>(qp, Kbuf, vT, kbias, nmask, out);
}

// Round 8
// 112.105 us; speedup vs baseline: 1.1781x; 1.0040x over previous
//
#include <hip/hip_runtime.h>

// Problem constants
#define BB 32
#define SS 512
#define DD 768
#define HH 12
#define HDIM 64
#define OL 256        // pooled query length
#define NQKV 2304     // 3*DD
#define GM (BB*SS)    // 16384 rows into the QKV GEMM

#define NEG2 (-14426.9504089f)   // -10000 * log2(e)

typedef __bf16 bf16_t;
typedef bf16_t bf16x8 __attribute__((ext_vector_type(8)));
typedef float f32x4 __attribute__((ext_vector_type(4)));
typedef unsigned short u16x8 __attribute__((ext_vector_type(8)));

__device__ __forceinline__ unsigned short f2bf(float f) {
  unsigned u = __float_as_uint(f);
  u = u + 0x7FFFu + ((u >> 16) & 1u);   // RNE
  return (unsigned short)(u >> 16);
}
__device__ __forceinline__ float b2f(unsigned short s) {
  return __uint_as_float(((unsigned)s) << 16);
}

// ---------------------------------------------------------------- conversions
__global__ void conv_f32_bf16(const float* __restrict__ in,
                              unsigned short* __restrict__ out, int n4) {
  int i = blockIdx.x * blockDim.x + threadIdx.x;
  if (i >= n4) return;
  float4 v = ((const float4*)in)[i];
  ushort4 o;
  o.x = f2bf(v.x); o.y = f2bf(v.y); o.z = f2bf(v.z); o.w = f2bf(v.w);
  ((ushort4*)out)[i] = o;
}

// ---------------------------------------------------------------- mask prep
// kbias pre-scaled by log2(e): 0 valid, -14427 masked.
__global__ void prep_mask(const void* __restrict__ mraw,
                          float* __restrict__ kbias,
                          float* __restrict__ invn,
                          unsigned char* __restrict__ nmask,
                          float* __restrict__ out_nm) {
  int b = blockIdx.x, t = threadIdx.x;
  const unsigned char* mb = (const unsigned char*)mraw;
  bool isbyte = (mb[1] != 0);
  int idx = b * SS + t;
  int mv = isbyte ? (int)(mb[idx] != 0) : (int)(((const int*)mraw)[idx] != 0);
  kbias[idx] = mv ? 0.f : NEG2;
  if (t < OL) {
    int i0 = b * SS + 2 * t, i1 = i0 + 1;
    int m0 = isbyte ? (int)(mb[i0] != 0) : (int)(((const int*)mraw)[i0] != 0);
    int m1 = isbyte ? (int)(mb[i1] != 0) : (int)(((const int*)mraw)[i1] != 0);
    int n = m0 + m1;
    invn[b * OL + t] = (n > 0) ? 1.f / (float)n : 1.f;
    nmask[b * OL + t] = (n > 0) ? 1 : 0;
    out_nm[b * OL + t] = (n > 0) ? 1.f : 0.f;   // second tuple output
  }
}

// ---------------------------------------------------------------- QKV GEMM
// 128x128 tile, BK=64, 4 waves (2M x 2N), dbuf LDS 64 KiB -> 2 blocks/CU.
// Counted-vmcnt pipeline, T2 XOR-swizzle, T5 setprio, T1 XCD swizzle.
// Fused epilogues: n-blocks 0-5 -> pooled qp; 6-11 -> Kbuf; 12-17 -> vT.
#define NT 12   // 768 / 64
__global__ __launch_bounds__(256, 2) void gemm_qkv(
    const unsigned short* __restrict__ A,
    const unsigned short* __restrict__ Bt,
    const float* __restrict__ bias,
    unsigned short* __restrict__ Kbuf,   // [B*S][768]
    unsigned short* __restrict__ qp,     // [B*OL][768]
    unsigned short* __restrict__ vT,     // [B][H][64][512]
    const float* __restrict__ kbias,
    const float* __restrict__ invn) {
  __shared__ __align__(16) char smem[65536];  // 2 x (A 16K + B 16K)

  const int t = threadIdx.x;
  const int lane = t & 63;
  const int w = t >> 6;          // 0..3
  const int wm = w >> 1, wn = w & 1;
  const int fr = lane & 15, hi = lane >> 4;

  // T1: bijective XCD-chunk swizzle; 2304 blocks = 8 XCDs x 288 (m-major)
  const int p = blockIdx.x;
  const int l = (p & 7) * 288 + (p >> 3);
  const int m0 = (l / 18) * 128;
  const int n0 = (l % 18) * 128;
  const int b = m0 >> 9;         // batch (128 | 512)
  const int s0 = m0 & 511;       // seq offset of row 0

  f32x4 acc[4][4] = {};

  const int sr8 = lane >> 3;                      // 0..7
  const int sx8 = ((lane & 7) ^ sr8) * 8;         // pre-swizzled src col
  const int wq = __builtin_amdgcn_readfirstlane(w);
  const unsigned short* aSrc = A + (size_t)(m0 + wq * 32 + sr8) * DD + sx8;
  const unsigned short* bSrc = Bt + (size_t)(n0 + wq * 32 + sr8) * DD + sx8;

#define GLOAD(SRC, DST)                                                        \
  __builtin_amdgcn_global_load_lds(                                           \
      (const __attribute__((address_space(1))) unsigned int*)(SRC),           \
      (__attribute__((address_space(3))) unsigned int*)(DST), 16, 0, 0)

  // 8 loads per wave per tile: 4 A-row-chunks + 4 B-row-chunks
#define STAGE(T) do {                                                          \
    char* da_ = smem + ((T) & 1) * 32768;                                      \
    char* db_ = da_ + 16384;                                                   \
    const unsigned short* as_ = aSrc + (T) * 64;                               \
    const unsigned short* bs_ = bSrc + (T) * 64;                               \
    _Pragma("unroll")                                                          \
    for (int i_ = 0; i_ < 4; ++i_) {                                           \
      GLOAD(as_ + (size_t)i_ * 8 * DD, da_ + (wq * 32 + i_ * 8) * 128);        \
      GLOAD(bs_ + (size_t)i_ * 8 * DD, db_ + (wq * 32 + i_ * 8) * 128);        \
    }                                                                          \
  } while (0)

  STAGE(0);
  STAGE(1);

  const int cb0 = (hi * 16) ^ ((fr & 7) << 4);
  const int cb1 = (64 + hi * 16) ^ ((fr & 7) << 4);

  for (int kt = 0; kt < NT; ++kt) {
    if (kt < NT - 1) {
      asm volatile("s_waitcnt vmcnt(8)" ::: "memory");
    } else {
      asm volatile("s_waitcnt vmcnt(0)" ::: "memory");
    }
    __builtin_amdgcn_sched_barrier(0);
    __builtin_amdgcn_s_barrier();
    __builtin_amdgcn_sched_barrier(0);

    const char* bA = smem + (kt & 1) * 32768;
    const char* bB = bA + 16384;

    bf16x8 a0[4], b0[4], a1[4], b1[4];
#pragma unroll
    for (int f = 0; f < 4; ++f) {
      a0[f] = *(const bf16x8*)(bA + (wm * 64 + f * 16 + fr) * 128 + cb0);
      b0[f] = *(const bf16x8*)(bB + (wn * 64 + f * 16 + fr) * 128 + cb0);
    }
    __builtin_amdgcn_sched_barrier(0);
#pragma unroll
    for (int f = 0; f < 4; ++f) {
      a1[f] = *(const bf16x8*)(bA + (wm * 64 + f * 16 + fr) * 128 + cb1);
      b1[f] = *(const bf16x8*)(bB + (wn * 64 + f * 16 + fr) * 128 + cb1);
    }
    asm volatile("s_waitcnt lgkmcnt(8)" ::: "memory");
    __builtin_amdgcn_sched_barrier(0);
    __builtin_amdgcn_s_setprio(1);
#pragma unroll
    for (int mf = 0; mf < 4; ++mf)
#pragma unroll
      for (int nf = 0; nf < 4; ++nf)
        acc[mf][nf] = __builtin_amdgcn_mfma_f32_16x16x32_bf16(
            a0[mf], b0[nf], acc[mf][nf], 0, 0, 0);
    __builtin_amdgcn_s_setprio(0);
    asm volatile("s_waitcnt lgkmcnt(0)" ::: "memory");
    __builtin_amdgcn_sched_barrier(0);
    __builtin_amdgcn_s_barrier();     // all waves done reading this buffer
    __builtin_amdgcn_sched_barrier(0);
    if (kt + 2 < NT) STAGE(kt + 2);   // writes this parity — now safe
    __builtin_amdgcn_sched_barrier(0);
    __builtin_amdgcn_s_setprio(1);
#pragma unroll
    for (int mf = 0; mf < 4; ++mf)
#pragma unroll
      for (int nf = 0; nf < 4; ++nf)
        acc[mf][nf] = __builtin_amdgcn_mfma_f32_16x16x32_bf16(
            a1[mf], b1[nf], acc[mf][nf], 0, 0, 0);
    __builtin_amdgcn_s_setprio(0);
  }
#undef STAGE
#undef GLOAD

  // ---------------- fused epilogues
  const int ntype = n0 / 768;   // 0=Q(pool), 1=K, 2=V(transpose)
  if (ntype == 1) {
#pragma unroll
    for (int nf = 0; nf < 4; ++nf) {
      const int nc = wn * 64 + nf * 16 + fr;
      const float bvs = bias[n0 + nc];
      const int gnc = n0 - 768 + nc;
#pragma unroll
      for (int mf = 0; mf < 4; ++mf) {
        const int gmr = m0 + wm * 64 + mf * 16 + hi * 4;
#pragma unroll
        for (int j = 0; j < 4; ++j)
          Kbuf[(size_t)(gmr + j) * 768 + gnc] = f2bf(acc[mf][nf][j] + bvs);
      }
    }
  } else if (ntype == 0) {
#pragma unroll
    for (int mf = 0; mf < 4; ++mf) {
      const int sl = s0 + wm * 64 + mf * 16 + hi * 4;   // seq of j=0
      const float4 km = *(const float4*)&kbias[b * SS + sl];
      const float2 iv = *(const float2*)&invn[b * OL + (sl >> 1)];
      const float w0 = (km.x == 0.f) ? iv.x : 0.f;
      const float w1 = (km.y == 0.f) ? iv.x : 0.f;
      const float w2 = (km.z == 0.f) ? iv.y : 0.f;
      const float w3 = (km.w == 0.f) ? iv.y : 0.f;
      const int o0 = b * OL + (sl >> 1);
#pragma unroll
      for (int nf = 0; nf < 4; ++nf) {
        const int gnc = n0 + wn * 64 + nf * 16 + fr;
        const float bvs = bias[gnc];
        const f32x4 a = acc[mf][nf];
        qp[(size_t)o0 * DD + gnc] = f2bf((a[0] + bvs) * w0 + (a[1] + bvs) * w1);
        qp[(size_t)(o0 + 1) * DD + gnc] = f2bf((a[2] + bvs) * w2 + (a[3] + bvs) * w3);
      }
    }
  } else {
    // V: bias + bf16 into LDS [128 n][136 m], then transposed coalesced store
    unsigned short* lt = (unsigned short*)smem;
#pragma unroll
    for (int nf = 0; nf < 4; ++nf) {
      const int nl = wn * 64 + nf * 16 + fr;
      const float bvs = bias[n0 + nl];
#pragma unroll
      for (int mf = 0; mf < 4; ++mf) {
        const int mb = wm * 64 + mf * 16 + hi * 4;
        ushort4 pk;
        pk.x = f2bf(acc[mf][nf][0] + bvs);
        pk.y = f2bf(acc[mf][nf][1] + bvs);
        pk.z = f2bf(acc[mf][nf][2] + bvs);
        pk.w = f2bf(acc[mf][nf][3] + bvs);
        *(ushort4*)&lt[nl * 136 + mb] = pk;
      }
    }
    __syncthreads();
#pragma unroll
    for (int i = 0; i < 8; ++i) {
      const int row = i * 16 + (t >> 4);
      const int ch = t & 15;
      const u16x8 v = *(const u16x8*)&lt[row * 136 + ch * 8];
      const int n = n0 - 1536 + row;
      const int h2 = n >> 6, d2 = n & 63;
      *(u16x8*)(vT + ((size_t)((b * HH + h2) * HDIM + d2)) * 512 + s0 + ch * 8) = v;
    }
  }
}

// ---------------------------------------------------------------- attention
// slopes pre-scaled by log2(e)
__constant__ float c_slopes2[12] = {
    0.72134752f, 0.36067376f, 0.18033688f, 0.09016844f,
    0.04508422f, 0.02254211f, 0.011271055f, 0.0056355275f,
    1.02013945f, 0.51006972f, 0.25503486f, 0.12751743f};

// 4-wave block; block covers HALF the q-rows of one (b,h): wave w owns
// 32 q-rows (2 m-frags). 768 blocks x 4 waves = 3072 waves = 3/SIMD.
// K/V dbuf shared across waves (4 loads/wave/tile, counted vmcnt(4)),
// per-wave P (4 KiB), fixed-max log2-domain softmax.
// LDS: kt dbuf 0..16K, vt dbuf 16..32K, P 32K + w*4K, kb @49152 (2K).
// Total 51200 B -> 3 blocks/CU. Epilogue reuses [0, 34816).
__global__ __launch_bounds__(256) void attn_mfma(
    const unsigned short* __restrict__ qp,    // [B][OL][768] bf16
    const unsigned short* __restrict__ Kb,    // [B*S][768] bf16
    const unsigned short* __restrict__ vT,    // [B][H][64][512] bf16
    const float* __restrict__ kbias,          // [B][S], pre-scaled log2e
    const unsigned char* __restrict__ nmask,  // [B][OL]
    float* __restrict__ out) {                // [B][OL][768]
  __shared__ __align__(16) char smem[51200];
  const int t = threadIdx.x;
  const int lane = t & 63;
  const int w = t >> 6;
  const int wq = __builtin_amdgcn_readfirstlane(w);
  const int fr = lane & 15, hi = lane >> 4;

  // 768 blocks = 8 XCDs x 96; consecutive logical ids share (b,h) -> L2 reuse
  const int p = blockIdx.x;
  const int l = (p & 7) * 96 + (p >> 3);
  const int qb = l & 1;
  const int bh = l >> 1;
  const int h = bh % HH, b = bh / HH;
  const int q0 = qb * 128 + wq * 32;    // this wave's first q-row

  char* ptb = smem + 32768 + wq * 4096;
  float* kbl = (float*)(smem + 49152);

  const int srow = lane >> 3;
  const int scol = ((lane & 7) ^ srow) * 8;

#define GLOAD(SRC, DST)                                                        \
  __builtin_amdgcn_global_load_lds(                                           \
      (const __attribute__((address_space(1))) unsigned int*)(SRC),           \
      (__attribute__((address_space(3))) unsigned int*)(DST), 16, 0, 0)

  // kbias row -> LDS via DMA (wave 0 only; 2 issues, drained by 1st vmcnt(4))
  if (wq == 0) {
    GLOAD(kbias + b * SS + lane * 4, smem + 49152);
    GLOAD(kbias + b * SS + 256 + lane * 4, smem + 50176);
  }

  // Q fragments: A-operand, row = q0+m*16+fr, k(d) = ks*32 + hi*8 (+0..7)
  bf16x8 qf[2][2];
#pragma unroll
  for (int m = 0; m < 2; ++m)
#pragma unroll
    for (int ks = 0; ks < 2; ++ks)
      qf[m][ks] = *(const bf16x8*)(qp + (size_t)(b * OL + q0 + m * 16 + fr) * DD +
                                   h * HDIM + ks * 32 + hi * 8);

  // one nmask byte per lane (32 rows -> lane&31), distribute via shuffles
  int nmv = (int)nmask[b * OL + q0 + (lane & 31)];
  int qmbits = 0;
#pragma unroll
  for (int m = 0; m < 2; ++m)
#pragma unroll
    for (int j = 0; j < 4; ++j)
      if (__shfl(nmv, m * 16 + hi * 4 + j, 64)) qmbits |= 1 << (m * 4 + j);

  const float slope2 = c_slopes2[h];
  f32x4 oacc[2][4] = {};
  float lpart[2][4] = {};

  // wave w stages K rows [w*16, w*16+16) and V rows [w*16, w*16+16)
#define STAGE(TILE, BUF) do {                                                  \
    char* kd_ = smem + (BUF) * 8192 + wq * 2048;                               \
    char* vd_ = smem + 16384 + (BUF) * 8192 + wq * 2048;                       \
    const unsigned short* ks_ =                                                \
        Kb + (size_t)(b * SS + (TILE) * 64 + wq * 16 + srow) * 768 + h * HDIM + scol; \
    const unsigned short* vs_ =                                                \
        vT + (size_t)((b * HH + h) * HDIM + wq * 16 + srow) * SS + (TILE) * 64 + scol; \
    GLOAD(ks_, kd_);                                                           \
    GLOAD(ks_ + (size_t)8 * 768, kd_ + 1024);                                  \
    GLOAD(vs_, vd_);                                                           \
    GLOAD(vs_ + (size_t)8 * SS, vd_ + 1024);                                   \
  } while (0)

  __builtin_amdgcn_sched_barrier(0);
  STAGE(0, 0);
  STAGE(1, 1);
  __builtin_amdgcn_sched_barrier(0);

  for (int tile = 0; tile < 8; ++tile) {
    const int cur = tile & 1;
    const int key0 = tile * 64;
    if (tile < 7) {
      asm volatile("s_waitcnt vmcnt(4)" ::: "memory");
    } else {
      asm volatile("s_waitcnt vmcnt(0)" ::: "memory");
    }
    __builtin_amdgcn_sched_barrier(0);
    __builtin_amdgcn_s_barrier();          // all waves' tile data landed
    __builtin_amdgcn_sched_barrier(0);

    char* ktb = smem + cur * 8192;
    char* vtb = smem + 16384 + cur * 8192;

    // ---- QK^T
    f32x4 sacc[2][4] = {};
#pragma unroll
    for (int ks = 0; ks < 2; ++ks) {
      bf16x8 kf[4];
#pragma unroll
      for (int n = 0; n < 4; ++n) {
        const int by = ((n * 16 + fr) * 128 + (ks * 64 + hi * 16)) ^ ((fr & 7) << 4);
        kf[n] = *(const bf16x8*)(ktb + by);
      }
#pragma unroll
      for (int m = 0; m < 2; ++m)
#pragma unroll
        for (int n = 0; n < 4; ++n)
          sacc[m][n] = __builtin_amdgcn_mfma_f32_16x16x32_bf16(qf[m][ks], kf[n], sacc[m][n], 0, 0, 0);
    }

    // ---- fixed-max log2-domain softmax; P -> LDS (bf16)
    float kbv[4], keyfv[4];
#pragma unroll
    for (int n = 0; n < 4; ++n) {
      kbv[n] = kbl[key0 + n * 16 + fr];
      keyfv[n] = (float)(key0 + n * 16 + fr);
    }
#pragma unroll
    for (int m = 0; m < 2; ++m) {
#pragma unroll
      for (int j = 0; j < 4; ++j) {
        const bool qm = (qmbits >> (m * 4 + j)) & 1;
        const float qvf = (float)(q0 + m * 16 + hi * 4 + j);
        float lp = lpart[m][j];
#pragma unroll
        for (int n = 0; n < 4; ++n) {
          const float biasv = qm ? kbv[n] : 0.f;
          const float rel = fabsf(keyfv[n] - qvf);
          float tv = fmaf(sacc[m][n][j], 0.18033688011f, biasv);
          tv = fmaf(rel, -slope2, tv);
          float pe;
          asm("v_exp_f32 %0, %1" : "=v"(pe) : "v"(tv));
          lp += pe;
          const int by = ((m * 16 + hi * 4 + j) * 128 + (n * 16 + fr) * 2) ^
                         (((hi * 4 + j) & 7) << 4);
          *(unsigned short*)(ptb + by) = f2bf(pe);
        }
        lpart[m][j] = lp;
      }
    }
    asm volatile("s_waitcnt lgkmcnt(0)" ::: "memory");
    __builtin_amdgcn_sched_barrier(0);

    // ---- PV
#pragma unroll
    for (int ks = 0; ks < 2; ++ks) {
      bf16x8 pf[2], vf[4];
#pragma unroll
      for (int m = 0; m < 2; ++m) {
        const int by = ((m * 16 + fr) * 128 + (ks * 64 + hi * 16)) ^ ((fr & 7) << 4);
        pf[m] = *(const bf16x8*)(ptb + by);
      }
#pragma unroll
      for (int nd = 0; nd < 4; ++nd) {
        const int by = ((nd * 16 + fr) * 128 + (ks * 64 + hi * 16)) ^ ((fr & 7) << 4);
        vf[nd] = *(const bf16x8*)(vtb + by);
      }
#pragma unroll
      for (int m = 0; m < 2; ++m)
#pragma unroll
        for (int nd = 0; nd < 4; ++nd)
          oacc[m][nd] = __builtin_amdgcn_mfma_f32_16x16x32_bf16(pf[m], vf[nd], oacc[m][nd], 0, 0, 0);
    }

    __builtin_amdgcn_sched_barrier(0);
    __builtin_amdgcn_s_barrier();          // all waves done reading buf `cur`
    __builtin_amdgcn_sched_barrier(0);
    if (tile + 2 < 8) STAGE(tile + 2, cur);
  }
#undef STAGE
#undef GLOAD

  // ---- epilogue: reduce l, normalize, transpose via per-wave LDS tile,
  //      coalesced stores. (last loop barrier guarantees LDS is free)
  float* ot = (float*)(smem + wq * 8704);   // 32 x 68 f32
#pragma unroll
  for (int m = 0; m < 2; ++m)
#pragma unroll
    for (int j = 0; j < 4; ++j) {
      float lv = lpart[m][j];
      lv += __shfl_xor(lv, 1, 64);
      lv += __shfl_xor(lv, 2, 64);
      lv += __shfl_xor(lv, 4, 64);
      lv += __shfl_xor(lv, 8, 64);
      const float rl = 1.f / lv;
      const int row = m * 16 + hi * 4 + j;
#pragma unroll
      for (int nd = 0; nd < 4; ++nd)
        ot[row * 68 + nd * 16 + fr] = oacc[m][nd][j] * rl;
    }
  asm volatile("s_waitcnt lgkmcnt(0)" ::: "memory");
  __builtin_amdgcn_sched_barrier(0);
#pragma unroll
  for (int i = 0; i < 8; ++i) {
    const int idx = i * 64 + lane;       // float4 index, 512 per wave
    const int row = idx >> 4, c4 = idx & 15;
    const float4 v = *(const float4*)&ot[row * 68 + c4 * 4];
    *(float4*)(out + (size_t)(b * OL + q0 + row) * DD + h * HDIM + c4 * 4) = v;
  }
}

// ---------------------------------------------------------------- launch
extern "C" void kernel_launch(void* const* d_in, const int* in_sizes, int n_in,
                              void* d_out, int out_size, void* d_ws, size_t ws_size,
                              hipStream_t stream) {
  const float* hidden = (const float*)d_in[0];
  const void* maskraw = d_in[1];
  const float* W = (const float*)d_in[2];
  const float* bias = (const float*)d_in[3];
  float* out = (float*)d_out;

  char* ws = (char*)d_ws;
  unsigned short* Abf  = (unsigned short*)(ws);                 // 25,165,824 B
  unsigned short* Btb  = (unsigned short*)(ws + 25165824);      //  3,538,944 B
  unsigned short* Kbuf = (unsigned short*)(ws + 28704768);      // 25,165,824 B
  unsigned short* vT   = (unsigned short*)(ws + 53870592);      // 25,165,824 B
  unsigned short* qp   = (unsigned short*)(ws + 79036416);      // 12,582,912 B
  float* kbias         = (float*)(ws + 91619328);               //     65,536 B
  float* invn          = (float*)(ws + 91684864);               //     32,768 B
  unsigned char* nmask = (unsigned char*)(ws + 91717632);       //      8,192 B

  float* out_nm = out + (size_t)BB * OL * DD;  // new_mask part of d_out

  conv_f32_bf16<<<(GM * DD / 4 + 255) / 256, 256, 0, stream>>>(hidden, Abf, GM * DD / 4);
  conv_f32_bf16<<<(NQKV * DD / 4 + 255) / 256, 256, 0, stream>>>(W, Btb, NQKV * DD / 4);
  prep_mask<<<BB, SS, 0, stream>>>(maskraw, kbias, invn, nmask, out_nm);
  gemm_qkv<<<2304, 256, 0, stream>>>(Abf, Btb, bias, Kbuf, qp, vT, kbias, invn);
  attn_mfma<<<768, 256, 0, stream>>>(qp, Kbuf, vT, kbias, nmask, out);
}